// Round 9
// baseline (759.424 us; speedup 1.0000x reference)
//
#include <hip/hip_runtime.h>

// RangeLoss, R9: single-pass fused reduction (last-block pattern).
// R8 post-mortem: R6/R7/R8 all land 201-203.5us (noise); max(stage1) pinned
// <59us. Total is dominated by ~142us fixed harness traffic (402MB poison
// fill + 201MB restore) and stage1 is co-limited by the HBM writeback drain
// of that traffic — kernel-internal changes no longer express in dur_us.
// Only remaining controllable serialized cost: the 2nd launch + serial
// stage2 (~5-8us). This version fuses them: per-block partial -> threadfence
// -> device-scope counter; last block re-reads the 48KB of partials (L2-hot)
// and writes out[0]. Counter at d_ws[0], zeroed via graph-safe memsetAsync.

#define N3      25165824                  // 8388608 * 3 floats
#define G4      6291456                   // N3 / 4 float4s
#define BLOCK   256
#define UNROLL  2
#define NB      (G4 / (BLOCK * UNROLL))   // 12288, exact
#define INV_TOTAL (1.0f / 25165824.0f)

typedef float vfloat4 __attribute__((ext_vector_type(4)));

__global__ void __launch_bounds__(BLOCK, 8) rangeloss_fused(
    const vfloat4* __restrict__ preds4,
    const vfloat4* __restrict__ target4,
    const float*   __restrict__ predsf,
    unsigned int*  __restrict__ counter,   // d_ws[0], pre-zeroed
    float*         __restrict__ partials,  // d_ws + 256B
    float*         __restrict__ out)
{
    const int tid  = threadIdx.x;
    const int lane = tid & 63;
    const int wv   = tid >> 6;
    const int base = blockIdx.x * (BLOCK * UNROLL) + tid;

    // ---- load phase: 4 dwordx4 per thread + 1 predicated dword on lane 63 ----
    vfloat4 p[UNROLL], t[UNROLL];
    float   pn63[UNROLL];
    #pragma unroll
    for (int k = 0; k < UNROLL; ++k) {
        const int i = base + k * BLOCK;
        p[k] = preds4[i];
        t[k] = __builtin_nontemporal_load(&target4[i]);   // read-once stream
        if (lane == 63)
            pn63[k] = predsf[min(4 * i + 4, N3 - 1)];     // wave-boundary neighbor
    }
    __builtin_amdgcn_sched_barrier(0);   // keep all loads issued before compute

    // ---- p_next: intra-wave shfl, lane 63 from its own load. No barrier. ----
    float pn[UNROLL];
    #pragma unroll
    for (int k = 0; k < UNROLL; ++k) {
        float nx = __shfl_down(p[k].x, 1, 64);
        pn[k] = (lane == 63) ? pn63[k] : nx;
    }

    // ---- compute ----
    float sum = 0.0f;
    #pragma unroll
    for (int k = 0; k < UNROLL; ++k) {
        const int i  = base + k * BLOCK;
        const int ph = i % 3;     // col of element 0 is (4i)%3 = i%3

        const float pe[4]  = {p[k].x, p[k].y, p[k].z, p[k].w};
        const float te[4]  = {t[k].x, t[k].y, t[k].z, t[k].w};
        const float pnx[4] = {p[k].y, p[k].z, p[k].w, pn[k]};

        #pragma unroll
        for (int e = 0; e < 4; ++e) {
            int col = ph + e;
            col = (col >= 3) ? col - 3 : col;             // (ph+e) mod 3
            const bool is_c1 = (col == 1);

            const float pp = pe[e], tt = te[e];
            const float diff = pp - tt;

            // col 0/2: target is exactly 0.0 or 1.0 -> snap iff |p-t| < 0.1
            const bool r02 = __builtin_fabsf(diff) < 0.1f;
            // col 1: snap iff p_next>0.9 or p*1.02>t && p*0.98<t (exact ref form)
            const bool inr = (pp * 1.02f > tt) && (pp * 0.98f < tt);
            const bool r1  = (pnx[e] > 0.9f) || inr;

            const bool snap = is_c1 ? r1 : r02;
            const float d = snap ? 0.0f : diff;           // snapped => diff exactly 0
            sum = fmaf(d, d, sum);
        }
    }

    sum *= INV_TOTAL;  // pre-scale so summed partials equal the mean

    // ---- block reduction ----
    #pragma unroll
    for (int off = 32; off > 0; off >>= 1)
        sum += __shfl_down(sum, off, 64);

    __shared__ float red[BLOCK / 64];
    __shared__ bool  amLast;
    if (lane == 0) red[wv] = sum;
    __syncthreads();

    if (tid == 0) {
        partials[blockIdx.x] = red[0] + red[1] + red[2] + red[3];
        __threadfence();                           // release: partial visible device-wide
        unsigned int old = atomicAdd(counter, 1u); // device-scope by default
        amLast = (old == NB - 1);
    }
    __syncthreads();

    // ---- last block: final reduction over all partials (48KB, L2-hot) ----
    if (amLast) {
        __threadfence();                           // acquire: see all partials
        float s = 0.0f;
        #pragma unroll
        for (int i = tid; i < NB; i += BLOCK)
            s += partials[i];

        #pragma unroll
        for (int off = 32; off > 0; off >>= 1)
            s += __shfl_down(s, off, 64);

        if (lane == 0) red[wv] = s;
        __syncthreads();
        if (tid == 0)
            out[0] = red[0] + red[1] + red[2] + red[3];  // overwrites poison
    }
}

extern "C" void kernel_launch(void* const* d_in, const int* in_sizes, int n_in,
                              void* d_out, int out_size, void* d_ws, size_t ws_size,
                              hipStream_t stream)
{
    const vfloat4* preds4  = (const vfloat4*)d_in[0];
    const vfloat4* target4 = (const vfloat4*)d_in[1];
    const float*   predsf  = (const float*)d_in[0];

    unsigned int* counter  = (unsigned int*)d_ws;            // 4B at offset 0
    float*        partials = (float*)((char*)d_ws + 256);    // NB floats, aligned
    float*        out      = (float*)d_out;

    // d_ws is re-poisoned to 0xAA before every replay: zero the counter in-stream.
    hipMemsetAsync(counter, 0, sizeof(unsigned int), stream);

    rangeloss_fused<<<NB, BLOCK, 0, stream>>>(preds4, target4, predsf,
                                              counter, partials, out);
}

// Round 10
// 201.343 us; speedup vs baseline: 3.7718x; 3.7718x over previous
//
#include <hip/hip_runtime.h>

// RangeLoss, R10: revert to R7 (best measured: 201.07us).
// R9 post-mortem: fused last-block reduction regressed 3.7x — VGPR fell to 16
// (compiler re-sank the loads; epilogue control flow defeated the sched_barrier
// hoist) and 12288 device-scope threadfence+atomic pairs serialized. Lesson:
// last-block fusion is strictly worse than a ~3us second launch here.
// R6/R7/R8 (three stage-1 structures) all measured 201-203.5us with stage-1
// pinned <59us — the controllable ~55us is at the contended-HBM floor
// (harness poison/restore writeback drain shares the bus). This is the
// best-known kernel; if it reproduces ~201us the session is at the roofline.

#define N3      25165824                  // 8388608 * 3 floats
#define G4      6291456                   // N3 / 4 float4s
#define BLOCK   256
#define UNROLL  2
#define NB      (G4 / (BLOCK * UNROLL))   // 12288, exact
#define INV_TOTAL (1.0f / 25165824.0f)

typedef float vfloat4 __attribute__((ext_vector_type(4)));

__global__ void __launch_bounds__(BLOCK, 8) rangeloss_stage1(
    const vfloat4* __restrict__ preds4,
    const vfloat4* __restrict__ target4,
    const float*   __restrict__ predsf,
    float* __restrict__ partials)
{
    const int tid  = threadIdx.x;
    const int lane = tid & 63;
    const int wv   = tid >> 6;
    const int base = blockIdx.x * (BLOCK * UNROLL) + tid;

    // ---- load phase: exactly 4 dwordx4 per thread, back-to-back ----
    vfloat4 p[UNROLL], t[UNROLL];
    #pragma unroll
    for (int k = 0; k < UNROLL; ++k) {
        const int i = base + k * BLOCK;
        p[k] = preds4[i];
        t[k] = __builtin_nontemporal_load(&target4[i]);   // read-once stream
    }

    // block-boundary neighbor: preds element just past this block's range.
    // Only consumed by tid==BLOCK-1 at k==UNROLL-1. 1 lane, 1 line.
    float edge = 0.0f;
    if (tid == BLOCK - 1) {
        const int nf = 4 * (blockIdx.x + 1) * (BLOCK * UNROLL);
        edge = predsf[min(nf, N3 - 1)];   // clamp: global-last element is col 2, unused
    }
    __builtin_amdgcn_sched_barrier(0);

    // ---- p_next exchange (no global pn loads) ----
    // pnext(tid,k) = p.x of float4 (i+1) = p[k].x of tid+1  (tid<255)
    //             = p[k+1].x of tid 0    (tid==255, k<UNROLL-1)
    //             = edge                 (tid==255, k==UNROLL-1)
    __shared__ float xs[4][UNROLL];       // [wave][chunk], lane-0 values
    if (lane == 0) {
        #pragma unroll
        for (int k = 0; k < UNROLL; ++k) xs[wv][k] = p[k].x;
    }
    __syncthreads();

    float pn[UNROLL];
    #pragma unroll
    for (int k = 0; k < UNROLL; ++k) {
        float nx = __shfl_down(p[k].x, 1, 64);            // lanes 0..62
        if (lane == 63) {
            if (wv < 3)                nx = xs[wv + 1][k];            // next wave's lane 0
            else if (k < UNROLL - 1)   nx = xs[0][k + 1];             // tid 0, next chunk
            else                       nx = edge;                     // next block
        }
        pn[k] = nx;
    }

    // ---- compute ----
    float sum = 0.0f;
    #pragma unroll
    for (int k = 0; k < UNROLL; ++k) {
        const int i  = base + k * BLOCK;
        const int ph = i % 3;     // col of element 0 is (4i)%3 = i%3

        const float pe[4]  = {p[k].x, p[k].y, p[k].z, p[k].w};
        const float te[4]  = {t[k].x, t[k].y, t[k].z, t[k].w};
        const float pnx[4] = {p[k].y, p[k].z, p[k].w, pn[k]};

        #pragma unroll
        for (int e = 0; e < 4; ++e) {
            int col = ph + e;
            col = (col >= 3) ? col - 3 : col;             // (ph+e) mod 3
            const bool is_c1 = (col == 1);

            const float pp = pe[e], tt = te[e];
            const float diff = pp - tt;

            // col 0/2: target is exactly 0.0 or 1.0 -> snap iff |p-t| < 0.1
            const bool r02 = __builtin_fabsf(diff) < 0.1f;
            // col 1: snap iff p_next>0.9 or p*1.02>t && p*0.98<t (exact ref form)
            const bool inr = (pp * 1.02f > tt) && (pp * 0.98f < tt);
            const bool r1  = (pnx[e] > 0.9f) || inr;

            const bool snap = is_c1 ? r1 : r02;
            const float d = snap ? 0.0f : diff;           // snapped => diff exactly 0
            sum = fmaf(d, d, sum);
        }
    }

    sum *= INV_TOTAL;  // pre-scale so summed partials equal the mean

    // wave-64 butterfly reduce
    #pragma unroll
    for (int off = 32; off > 0; off >>= 1)
        sum += __shfl_down(sum, off, 64);

    __shared__ float red[BLOCK / 64];
    if (lane == 0) red[wv] = sum;
    __syncthreads();

    if (tid == 0)
        partials[blockIdx.x] = red[0] + red[1] + red[2] + red[3];
}

#define S2BLOCK 1024

__global__ void __launch_bounds__(S2BLOCK) rangeloss_stage2(
    const float* __restrict__ partials,
    float* __restrict__ out)
{
    float sum = 0.0f;
    #pragma unroll
    for (int i = threadIdx.x; i < NB; i += S2BLOCK)
        sum += partials[i];

    #pragma unroll
    for (int off = 32; off > 0; off >>= 1)
        sum += __shfl_down(sum, off, 64);

    __shared__ float smem[S2BLOCK / 64];
    const int lane = threadIdx.x & 63;
    const int wave = threadIdx.x >> 6;
    if (lane == 0) smem[wave] = sum;
    __syncthreads();

    if (threadIdx.x == 0) {
        float s = 0.0f;
        #pragma unroll
        for (int w = 0; w < S2BLOCK / 64; ++w) s += smem[w];
        out[0] = s;  // overwrites poison
    }
}

extern "C" void kernel_launch(void* const* d_in, const int* in_sizes, int n_in,
                              void* d_out, int out_size, void* d_ws, size_t ws_size,
                              hipStream_t stream)
{
    const vfloat4* preds4  = (const vfloat4*)d_in[0];
    const vfloat4* target4 = (const vfloat4*)d_in[1];
    const float*   predsf  = (const float*)d_in[0];
    float* partials = (float*)d_ws;   // NB floats = 48 KB, fully written by stage 1
    float* out = (float*)d_out;

    rangeloss_stage1<<<NB, BLOCK, 0, stream>>>(preds4, target4, predsf, partials);
    rangeloss_stage2<<<1, S2BLOCK, 0, stream>>>(partials, out);
}